// Round 5
// baseline (356.222 us; speedup 1.0000x reference)
//
#include <hip/hip_runtime.h>
#include <hip/hip_bf16.h>

typedef float f4  __attribute__((ext_vector_type(4)));
typedef short s8v __attribute__((ext_vector_type(8)));
typedef short s4v __attribute__((ext_vector_type(4)));

#define MFMA16(a, b, c) __builtin_amdgcn_mfma_f32_16x16x32_bf16((a), (b), (c), 0, 0, 0)

// Packed RNE f32->bf16 pair via compiler intrinsic (emits v_cvt_pk_bf16_f32).
// (__builtin_bit_cast rejects __hip_bfloat162: not trivially copyable on this
// ROCm -> extract via memcpy, which folds to a register reinterpret.)
__device__ __forceinline__ unsigned cvtpk(float a, float b) {
  __hip_bfloat162 h2 = __float22bfloat162_rn(make_float2(a, b));
  unsigned u;
  __builtin_memcpy(&u, &h2, 4);
  return u;
}
__device__ __forceinline__ float bf2f(unsigned short s) {
  union { unsigned u; float f; } x; x.u = ((unsigned)s) << 16; return x.f;
}
__device__ __forceinline__ s8v cvt8(const float* p) {
  float4 a = *(const float4*)p;
  float4 b = *(const float4*)(p + 4);
  union { unsigned u[4]; s8v v; } r;
  r.u[0] = cvtpk(a.x, a.y); r.u[1] = cvtpk(a.z, a.w);
  r.u[2] = cvtpk(b.x, b.y); r.u[3] = cvtpk(b.z, b.w);
  return r.v;
}
__device__ __forceinline__ s8v mk8(unsigned a0, unsigned a1, unsigned b0, unsigned b1) {
  union { unsigned u[4]; s8v v; } r;
  r.u[0] = a0; r.u[1] = a1; r.u[2] = b0; r.u[3] = b1;
  return r.v;
}
// Two b64 LDS reads -> one 8-bf16 A-operand (slots j0..3 from p0, j4..7 from p1).
__device__ __forceinline__ s8v ld44(const short* p0, const short* p1) {
  s4v a = *(const s4v*)p0;
  s4v b = *(const s4v*)p1;
  s8v r;
  r[0] = a[0]; r[1] = a[1]; r[2] = a[2]; r[3] = a[3];
  r[4] = b[0]; r[5] = b[1]; r[6] = b[2]; r[7] = b[3];
  return r;
}

__global__ __launch_bounds__(256, 5)
void attn_head(const void* __restrict__ xg, const void* __restrict__ wqg,
               const void* __restrict__ wkg, const void* __restrict__ wvg,
               void* __restrict__ outg) {
  // LDS exactly 32768 B -> 5 blocks/CU (160 KiB / 32 KiB).
  // Ks: K[s][h] at s*64 + (h ^ ((s&15)<<2))   (XOR swizzle, 8B granules)
  // Vt: V^T[h][s] at h*128 + (s ^ ((h&15)<<2))
  // All 8B accesses: 4 lanes/bank-pair uniform = conflict-free for b64.
  __shared__ __align__(16) short smem[16384];
  short* Ksm = smem;           // 128*64 shorts
  short* Vt  = smem + 8192;    // 64*128 shorts

  const int tid  = threadIdx.x;
  const int wave = tid >> 6;
  const int lane = tid & 63;
  const int c16  = lane & 15;
  const int quad = lane >> 4;
  const int b    = blockIdx.x;
  const int swz  = c16 << 2;

  // ---- barrier-free dtype detect: every wave samples the SAME 64 shorts ----
  // bf16 weights read as bf16 -> ~100% plausible magnitude; fp32 reinterpreted
  // -> mantissa-half shorts are garbage (~55% plausible). Threshold 58/64.
  int isbf;
  {
    const unsigned short* w = (const unsigned short*)wqg;
    float f = bf2f(w[lane]);
    float a = fabsf(f);
    int ok = (f == 0.0f || (a >= 1e-4f && a <= 1e4f)) ? 1 : 0;
    unsigned long long ball = __ballot(ok);
    isbf = (__popcll(ball) >= 58) ? 1 : 0;
  }

  const int mts[2] = {wave, 7 - wave};   // balanced causal split

  // ---- X fragments (A for V, B for Q^T/K^T) ----
  s8v xf[2][2];
  #pragma unroll
  for (int mi = 0; mi < 2; mi++) {
    const size_t base = (size_t)b * (128 * 64) + (size_t)(mts[mi] * 16 + c16) * 64;
    #pragma unroll
    for (int kt = 0; kt < 2; kt++) {
      const int off = kt * 32 + quad * 8;
      if (isbf) xf[mi][kt] = *(const s8v*)((const unsigned short*)xg + base + off);
      else      xf[mi][kt] = cvt8((const float*)xg + base + off);
    }
  }

  // ---- phase 1: Q^T,K^T (W-major MFMA), V (X-major) ----
  f4 QT[2][4];
  #pragma unroll
  for (int ht = 0; ht < 4; ht++) {
    s8v wqf[2], wkf[2], wvf[2];
    const int woff0 = (ht * 16 + c16) * 64 + quad * 8;
    #pragma unroll
    for (int kt = 0; kt < 2; kt++) {
      const int off = woff0 + kt * 32;
      if (isbf) {
        wqf[kt] = *(const s8v*)((const unsigned short*)wqg + off);
        wkf[kt] = *(const s8v*)((const unsigned short*)wkg + off);
        wvf[kt] = *(const s8v*)((const unsigned short*)wvg + off);
      } else {
        wqf[kt] = cvt8((const float*)wqg + off);
        wkf[kt] = cvt8((const float*)wkg + off);
        wvf[kt] = cvt8((const float*)wvg + off);
      }
    }
    #pragma unroll
    for (int mi = 0; mi < 2; mi++) {
      const int m = mts[mi];
      f4 z = {0.f, 0.f, 0.f, 0.f};
      f4 qt = z, kk = z, vv = z;
      qt = MFMA16(wqf[0], xf[mi][0], qt);  qt = MFMA16(wqf[1], xf[mi][1], qt);
      // swapped operands: lane holds h = ht*16+quad*4+r for s = m*16+c16
      kk = MFMA16(wkf[0], xf[mi][0], kk);  kk = MFMA16(wkf[1], xf[mi][1], kk);
      vv = MFMA16(xf[mi][0], wvf[0], vv);  vv = MFMA16(xf[mi][1], wvf[1], vv);
      QT[mi][ht] = qt;
      {  // K[s][h]: 4 consecutive h -> one 8B swizzled store
        union { unsigned u[2]; s4v v; } pk;
        pk.u[0] = cvtpk(kk[0], kk[1]); pk.u[1] = cvtpk(kk[2], kk[3]);
        *(s4v*)(Ksm + (m * 16 + c16) * 64 + ((ht * 16 + quad * 4) ^ swz)) = pk.v;
      }
      {  // V^T[h][s]: 4 consecutive s -> one 8B swizzled store
        union { unsigned u[2]; s4v v; } pv;
        pv.u[0] = cvtpk(vv[0], vv[1]); pv.u[1] = cvtpk(vv[2], vv[3]);
        *(s4v*)(Vt + (ht * 16 + c16) * 128 + ((m * 16 + quad * 4) ^ swz)) = pv.v;
      }
    }
  }

  // ---- Q B-operand frags, packed lane-local BEFORE the barrier ----
  // Slot-aligned contraction: Q^T C-layout feeds the B operand directly as
  // long as the A operand (K rows from LDS) uses the matching slot map.
  s8v qb[2][2];
  #pragma unroll
  for (int mi = 0; mi < 2; mi++)
    #pragma unroll
    for (int hp = 0; hp < 2; hp++)
      qb[mi][hp] = mk8(
          cvtpk(QT[mi][2*hp][0]   * 0.125f, QT[mi][2*hp][1]   * 0.125f),
          cvtpk(QT[mi][2*hp][2]   * 0.125f, QT[mi][2*hp][3]   * 0.125f),
          cvtpk(QT[mi][2*hp+1][0] * 0.125f, QT[mi][2*hp+1][1] * 0.125f),
          cvtpk(QT[mi][2*hp+1][2] * 0.125f, QT[mi][2*hp+1][3] * 0.125f));

  __syncthreads();   // only barrier

  // ---- phase 2 per M-tile: S^T -> exp/sum -> O^T = V^T·P^T ----
  #pragma unroll
  for (int mi = 0; mi < 2; mi++) {
    const int m = mts[mi];
    const int q4 = quad * 4;

    f4 S[8];
    #pragma unroll
    for (int nt = 0; nt < 8; nt++) {
      if (nt > m) continue;                 // wave-uniform causal skip
      const short* kr = Ksm + (nt * 16 + c16) * 64;
      f4 s = {0.f, 0.f, 0.f, 0.f};
      s = MFMA16(ld44(kr + ((q4     ) ^ swz), kr + ((q4 + 16) ^ swz)), qb[mi][0], s);
      s = MFMA16(ld44(kr + ((q4 + 32) ^ swz), kr + ((q4 + 48) ^ swz)), qb[mi][1], s);
      S[nt] = s;
    }

    float sum = 0.f;
    #pragma unroll
    for (int nt = 0; nt < 8; nt++) {
      if (nt > m) continue;
      #pragma unroll
      for (int r = 0; r < 4; r++) {
        const bool keep = (nt < m) || (q4 + r <= c16);
        float e = keep ? __expf(S[nt][r]) : 0.0f;
        S[nt][r] = e;
        sum += e;
      }
    }
    sum += __shfl_xor(sum, 16);
    sum += __shfl_xor(sum, 32);
    const float inv = 1.0f / sum;           // normalize in epilogue

    unsigned ppk[8][2];
    #pragma unroll
    for (int nt = 0; nt < 8; nt++) {
      if (nt > m) continue;
      ppk[nt][0] = cvtpk(S[nt][0], S[nt][1]);
      ppk[nt][1] = cvtpk(S[nt][2], S[nt][3]);
    }

    f4 acc[4];
    #pragma unroll
    for (int ht = 0; ht < 4; ht++) { f4 z = {0.f,0.f,0.f,0.f}; acc[ht] = z; }
    const int nchunk = (m >> 1) + 1;
    #pragma unroll
    for (int kt = 0; kt < 4; kt++) {
      if (kt >= nchunk) continue;           // wave-uniform causal K-range
      const bool hb = (2 * kt + 1) <= m;
      const s8v pb = mk8(ppk[2 * kt][0], ppk[2 * kt][1],
                         hb ? ppk[2 * kt + 1][0] : 0u,
                         hb ? ppk[2 * kt + 1][1] : 0u);
      #pragma unroll
      for (int ht = 0; ht < 4; ht++) {
        const short* vr = Vt + (ht * 16 + c16) * 128;
        const s8v va = ld44(vr + ((kt * 32 + q4     ) ^ swz),
                            vr + ((kt * 32 + q4 + 16) ^ swz));
        acc[ht] = MFMA16(va, pb, acc[ht]);
      }
    }

    // epilogue: O^T lane holds 4 consecutive h for query t=c16 -> 8/16B stores
    if (isbf) {
      unsigned short* op = (unsigned short*)outg + (size_t)b * (128 * 64);
      #pragma unroll
      for (int ht = 0; ht < 4; ht++) {
        union { unsigned u[2]; s4v v; } o;
        o.u[0] = cvtpk(acc[ht][0] * inv, acc[ht][1] * inv);
        o.u[1] = cvtpk(acc[ht][2] * inv, acc[ht][3] * inv);
        *(s4v*)(op + (size_t)(m * 16 + c16) * 64 + ht * 16 + q4) = o.v;
      }
    } else {
      float* op = (float*)outg + (size_t)b * (128 * 64);
      #pragma unroll
      for (int ht = 0; ht < 4; ht++) {
        float4 o = {acc[ht][0] * inv, acc[ht][1] * inv,
                    acc[ht][2] * inv, acc[ht][3] * inv};
        *(float4*)(op + (size_t)(m * 16 + c16) * 64 + ht * 16 + q4) = o;
      }
    }
  }
}

extern "C" void kernel_launch(void* const* d_in, const int* in_sizes, int n_in,
                              void* d_out, int out_size, void* d_ws, size_t ws_size,
                              hipStream_t stream) {
  (void)d_ws; (void)ws_size; (void)in_sizes; (void)n_in; (void)out_size;
  attn_head<<<dim3(4096), dim3(256), 0, stream>>>(
      d_in[0], d_in[1], d_in[2], d_in[3], d_out);
}

// Round 6
// 323.755 us; speedup vs baseline: 1.1003x; 1.1003x over previous
//
#include <hip/hip_runtime.h>
#include <hip/hip_bf16.h>

typedef float f4  __attribute__((ext_vector_type(4)));
typedef short s8v __attribute__((ext_vector_type(8)));
typedef short s4v __attribute__((ext_vector_type(4)));

#define MFMA16(a, b, c) __builtin_amdgcn_mfma_f32_16x16x32_bf16((a), (b), (c), 0, 0, 0)

// Packed RNE f32->bf16 pair via compiler intrinsic (emits v_cvt_pk_bf16_f32).
__device__ __forceinline__ unsigned cvtpk(float a, float b) {
  __hip_bfloat162 h2 = __float22bfloat162_rn(make_float2(a, b));
  unsigned u;
  __builtin_memcpy(&u, &h2, 4);
  return u;
}
__device__ __forceinline__ float bf2f(unsigned short s) {
  union { unsigned u; float f; } x; x.u = ((unsigned)s) << 16; return x.f;
}
__device__ __forceinline__ s8v cvt8(const float* p) {
  float4 a = *(const float4*)p;
  float4 b = *(const float4*)(p + 4);
  union { unsigned u[4]; s8v v; } r;
  r.u[0] = cvtpk(a.x, a.y); r.u[1] = cvtpk(a.z, a.w);
  r.u[2] = cvtpk(b.x, b.y); r.u[3] = cvtpk(b.z, b.w);
  return r.v;
}
__device__ __forceinline__ s8v mk8(unsigned a0, unsigned a1, unsigned b0, unsigned b1) {
  union { unsigned u[4]; s8v v; } r;
  r.u[0] = a0; r.u[1] = a1; r.u[2] = b0; r.u[3] = b1;
  return r.v;
}
// Two b64 LDS reads -> one 8-bf16 A-operand (slots j0..3 from p0, j4..7 from p1).
__device__ __forceinline__ s8v ld44(const short* p0, const short* p1) {
  s4v a = *(const s4v*)p0;
  s4v b = *(const s4v*)p1;
  s8v r;
  r[0] = a[0]; r[1] = a[1]; r[2] = a[2]; r[3] = a[3];
  r[4] = b[0]; r[5] = b[1]; r[6] = b[2]; r[7] = b[3];
  return r;
}

// launch_bounds(256,4): VGPR cap 128. R5's (256,5) clamped VGPR to 48 ->
// ~290 MB scratch spill traffic (FETCH 66->160MB, WRITE 131->330MB), 205us.
// Kernel needs ~72 VGPR <= 102, so 5 blocks/CU stays reachable via LDS=32KiB.
__global__ __launch_bounds__(256, 4)
void attn_head(const void* __restrict__ xg, const void* __restrict__ wqg,
               const void* __restrict__ wkg, const void* __restrict__ wvg,
               void* __restrict__ outg) {
  // LDS exactly 32768 B -> 5 blocks/CU (160 KiB / 32 KiB).
  // Ks: K[s][h] at s*64 + (h ^ ((s&15)<<2))   (XOR swizzle, 8B granules)
  // Vt: V^T[h][s] at h*128 + (s ^ ((h&15)<<2))
  // All 8B accesses: 4 lanes/bank-pair uniform = conflict-free for b64
  // (R5 measured SQ_LDS_BANK_CONFLICT = 0).
  __shared__ __align__(16) short smem[16384];
  short* Ksm = smem;           // 128*64 shorts
  short* Vt  = smem + 8192;    // 64*128 shorts

  const int tid  = threadIdx.x;
  const int wave = tid >> 6;
  const int lane = tid & 63;
  const int c16  = lane & 15;
  const int quad = lane >> 4;
  const int b    = blockIdx.x;
  const int swz  = c16 << 2;

  // ---- barrier-free dtype detect: every wave samples the SAME 64 shorts ----
  int isbf;
  {
    const unsigned short* w = (const unsigned short*)wqg;
    float f = bf2f(w[lane]);
    float a = fabsf(f);
    int ok = (f == 0.0f || (a >= 1e-4f && a <= 1e4f)) ? 1 : 0;
    unsigned long long ball = __ballot(ok);
    isbf = (__popcll(ball) >= 58) ? 1 : 0;
  }

  const int mts[2] = {wave, 7 - wave};   // balanced causal split

  // ---- X fragments (A for V, B for Q^T/K^T) ----
  s8v xf[2][2];
  #pragma unroll
  for (int mi = 0; mi < 2; mi++) {
    const size_t base = (size_t)b * (128 * 64) + (size_t)(mts[mi] * 16 + c16) * 64;
    #pragma unroll
    for (int kt = 0; kt < 2; kt++) {
      const int off = kt * 32 + quad * 8;
      if (isbf) xf[mi][kt] = *(const s8v*)((const unsigned short*)xg + base + off);
      else      xf[mi][kt] = cvt8((const float*)xg + base + off);
    }
  }

  // ---- phase 1: Q^T,K^T (W-major MFMA), V (X-major) ----
  f4 QT[2][4];
  #pragma unroll
  for (int ht = 0; ht < 4; ht++) {
    s8v wqf[2], wkf[2], wvf[2];
    const int woff0 = (ht * 16 + c16) * 64 + quad * 8;
    #pragma unroll
    for (int kt = 0; kt < 2; kt++) {
      const int off = woff0 + kt * 32;
      if (isbf) {
        wqf[kt] = *(const s8v*)((const unsigned short*)wqg + off);
        wkf[kt] = *(const s8v*)((const unsigned short*)wkg + off);
        wvf[kt] = *(const s8v*)((const unsigned short*)wvg + off);
      } else {
        wqf[kt] = cvt8((const float*)wqg + off);
        wkf[kt] = cvt8((const float*)wkg + off);
        wvf[kt] = cvt8((const float*)wvg + off);
      }
    }
    #pragma unroll
    for (int mi = 0; mi < 2; mi++) {
      const int m = mts[mi];
      f4 z = {0.f, 0.f, 0.f, 0.f};
      f4 qt = z, kk = z, vv = z;
      qt = MFMA16(wqf[0], xf[mi][0], qt);  qt = MFMA16(wqf[1], xf[mi][1], qt);
      // swapped operands: lane holds h = ht*16+quad*4+r for s = m*16+c16
      kk = MFMA16(wkf[0], xf[mi][0], kk);  kk = MFMA16(wkf[1], xf[mi][1], kk);
      vv = MFMA16(xf[mi][0], wvf[0], vv);  vv = MFMA16(xf[mi][1], wvf[1], vv);
      QT[mi][ht] = qt;
      {  // K[s][h]: 4 consecutive h -> one 8B swizzled store
        union { unsigned u[2]; s4v v; } pk;
        pk.u[0] = cvtpk(kk[0], kk[1]); pk.u[1] = cvtpk(kk[2], kk[3]);
        *(s4v*)(Ksm + (m * 16 + c16) * 64 + ((ht * 16 + quad * 4) ^ swz)) = pk.v;
      }
      {  // V^T[h][s]: 4 consecutive s -> one 8B swizzled store
        union { unsigned u[2]; s4v v; } pv;
        pv.u[0] = cvtpk(vv[0], vv[1]); pv.u[1] = cvtpk(vv[2], vv[3]);
        *(s4v*)(Vt + (ht * 16 + c16) * 128 + ((m * 16 + quad * 4) ^ swz)) = pv.v;
      }
    }
  }

  // ---- Q B-operand frags, packed lane-local BEFORE the barrier ----
  s8v qb[2][2];
  #pragma unroll
  for (int mi = 0; mi < 2; mi++)
    #pragma unroll
    for (int hp = 0; hp < 2; hp++)
      qb[mi][hp] = mk8(
          cvtpk(QT[mi][2*hp][0]   * 0.125f, QT[mi][2*hp][1]   * 0.125f),
          cvtpk(QT[mi][2*hp][2]   * 0.125f, QT[mi][2*hp][3]   * 0.125f),
          cvtpk(QT[mi][2*hp+1][0] * 0.125f, QT[mi][2*hp+1][1] * 0.125f),
          cvtpk(QT[mi][2*hp+1][2] * 0.125f, QT[mi][2*hp+1][3] * 0.125f));

  __syncthreads();   // only barrier

  // ---- phase 2 per M-tile: S^T -> exp/sum -> O^T = V^T·P^T ----
  #pragma unroll
  for (int mi = 0; mi < 2; mi++) {
    const int m = mts[mi];
    const int q4 = quad * 4;

    f4 S[8];
    #pragma unroll
    for (int nt = 0; nt < 8; nt++) {
      if (nt > m) continue;                 // wave-uniform causal skip
      const short* kr = Ksm + (nt * 16 + c16) * 64;
      f4 s = {0.f, 0.f, 0.f, 0.f};
      s = MFMA16(ld44(kr + ((q4     ) ^ swz), kr + ((q4 + 16) ^ swz)), qb[mi][0], s);
      s = MFMA16(ld44(kr + ((q4 + 32) ^ swz), kr + ((q4 + 48) ^ swz)), qb[mi][1], s);
      S[nt] = s;
    }

    float sum = 0.f;
    #pragma unroll
    for (int nt = 0; nt < 8; nt++) {
      if (nt > m) continue;
      #pragma unroll
      for (int r = 0; r < 4; r++) {
        const bool keep = (nt < m) || (q4 + r <= c16);
        float e = keep ? __expf(S[nt][r]) : 0.0f;
        S[nt][r] = e;
        sum += e;
      }
    }
    sum += __shfl_xor(sum, 16);
    sum += __shfl_xor(sum, 32);
    const float inv = 1.0f / sum;           // normalize in epilogue

    unsigned ppk[8][2];
    #pragma unroll
    for (int nt = 0; nt < 8; nt++) {
      if (nt > m) continue;
      ppk[nt][0] = cvtpk(S[nt][0], S[nt][1]);
      ppk[nt][1] = cvtpk(S[nt][2], S[nt][3]);
    }

    f4 acc[4];
    #pragma unroll
    for (int ht = 0; ht < 4; ht++) { f4 z = {0.f,0.f,0.f,0.f}; acc[ht] = z; }
    const int nchunk = (m >> 1) + 1;
    #pragma unroll
    for (int kt = 0; kt < 4; kt++) {
      if (kt >= nchunk) continue;           // wave-uniform causal K-range
      const bool hb = (2 * kt + 1) <= m;
      const s8v pb = mk8(ppk[2 * kt][0], ppk[2 * kt][1],
                         hb ? ppk[2 * kt + 1][0] : 0u,
                         hb ? ppk[2 * kt + 1][1] : 0u);
      #pragma unroll
      for (int ht = 0; ht < 4; ht++) {
        const short* vr = Vt + (ht * 16 + c16) * 128;
        const s8v va = ld44(vr + ((kt * 32 + q4     ) ^ swz),
                            vr + ((kt * 32 + q4 + 16) ^ swz));
        acc[ht] = MFMA16(va, pb, acc[ht]);
      }
    }

    // epilogue: O^T lane holds 4 consecutive h for query t=c16 -> 8/16B stores
    if (isbf) {
      unsigned short* op = (unsigned short*)outg + (size_t)b * (128 * 64);
      #pragma unroll
      for (int ht = 0; ht < 4; ht++) {
        union { unsigned u[2]; s4v v; } o;
        o.u[0] = cvtpk(acc[ht][0] * inv, acc[ht][1] * inv);
        o.u[1] = cvtpk(acc[ht][2] * inv, acc[ht][3] * inv);
        *(s4v*)(op + (size_t)(m * 16 + c16) * 64 + ht * 16 + q4) = o.v;
      }
    } else {
      float* op = (float*)outg + (size_t)b * (128 * 64);
      #pragma unroll
      for (int ht = 0; ht < 4; ht++) {
        float4 o = {acc[ht][0] * inv, acc[ht][1] * inv,
                    acc[ht][2] * inv, acc[ht][3] * inv};
        *(float4*)(op + (size_t)(m * 16 + c16) * 64 + ht * 16 + q4) = o;
      }
    }
  }
}

extern "C" void kernel_launch(void* const* d_in, const int* in_sizes, int n_in,
                              void* d_out, int out_size, void* d_ws, size_t ws_size,
                              hipStream_t stream) {
  (void)d_ws; (void)ws_size; (void)in_sizes; (void)n_in; (void)out_size;
  attn_head<<<dim3(4096), dim3(256), 0, stream>>>(
      d_in[0], d_in[1], d_in[2], d_in[3], d_out);
}

// Round 15
// 310.552 us; speedup vs baseline: 1.1471x; 1.0425x over previous
//
#include <hip/hip_runtime.h>
#include <hip/hip_bf16.h>

typedef float f4  __attribute__((ext_vector_type(4)));
typedef short s8v __attribute__((ext_vector_type(8)));
typedef short s4v __attribute__((ext_vector_type(4)));

#define MFMA16(a, b, c) __builtin_amdgcn_mfma_f32_16x16x32_bf16((a), (b), (c), 0, 0, 0)

// Packed RNE f32->bf16 pair via compiler intrinsic (emits v_cvt_pk_bf16_f32).
__device__ __forceinline__ unsigned cvtpk(float a, float b) {
  __hip_bfloat162 h2 = __float22bfloat162_rn(make_float2(a, b));
  unsigned u;
  __builtin_memcpy(&u, &h2, 4);
  return u;
}
__device__ __forceinline__ float bf2f(unsigned short s) {
  union { unsigned u; float f; } x; x.u = ((unsigned)s) << 16; return x.f;
}
__device__ __forceinline__ s8v cvt8(const float* p) {
  float4 a = *(const float4*)p;
  float4 b = *(const float4*)(p + 4);
  union { unsigned u[4]; s8v v; } r;
  r.u[0] = cvtpk(a.x, a.y); r.u[1] = cvtpk(a.z, a.w);
  r.u[2] = cvtpk(b.x, b.y); r.u[3] = cvtpk(b.z, b.w);
  return r.v;
}
__device__ __forceinline__ s8v mk8(unsigned a0, unsigned a1, unsigned b0, unsigned b1) {
  union { unsigned u[4]; s8v v; } r;
  r.u[0] = a0; r.u[1] = a1; r.u[2] = b0; r.u[3] = b1;
  return r.v;
}
// Two b64 LDS reads -> one 8-bf16 A-operand (slots j0..3 from p0, j4..7 from p1).
__device__ __forceinline__ s8v ld44(const short* p0, const short* p1) {
  s4v a = *(const s4v*)p0;
  s4v b = *(const s4v*)p1;
  s8v r;
  r[0] = a[0]; r[1] = a[1]; r[2] = a[2]; r[3] = a[3];
  r[4] = b[0]; r[5] = b[1]; r[6] = b[2]; r[7] = b[3];
  return r;
}

// launch_bounds min-waves: empirical VGPR cap on this toolchain is ~256/w
// (NOT 512/w): (256,5)->48 VGPR heavy spill (R5), (256,4)->64 VGPR spill
// (R6: +75MB WRITE), (256,3)->72 VGPR NO spill (R2). Use 3: cap ~85 >= the
// ~72 this kernel needs, and 72 <= 102 keeps 5 blocks/CU (LDS-limited).
__global__ __launch_bounds__(256, 3)
void attn_head(const void* __restrict__ xg, const void* __restrict__ wqg,
               const void* __restrict__ wkg, const void* __restrict__ wvg,
               void* __restrict__ outg) {
  // LDS exactly 32768 B -> 5 blocks/CU (160 KiB / 32 KiB).
  // Ks: K[s][h] at s*64 + (h ^ ((s&15)<<2))   (XOR swizzle, 8B granules)
  // Vt: V^T[h][s] at h*128 + (s ^ ((h&15)<<2))
  // All 8B accesses: 4 lanes/bank-pair uniform = conflict-free for b64
  // (R5/R6 measured SQ_LDS_BANK_CONFLICT = 0).
  __shared__ __align__(16) short smem[16384];
  short* Ksm = smem;           // 128*64 shorts
  short* Vt  = smem + 8192;    // 64*128 shorts

  const int tid  = threadIdx.x;
  const int wave = tid >> 6;
  const int lane = tid & 63;
  const int c16  = lane & 15;
  const int quad = lane >> 4;
  const int b    = blockIdx.x;
  const int swz  = c16 << 2;

  // ---- barrier-free dtype detect: every wave samples the SAME 64 shorts ----
  int isbf;
  {
    const unsigned short* w = (const unsigned short*)wqg;
    float f = bf2f(w[lane]);
    float a = fabsf(f);
    int ok = (f == 0.0f || (a >= 1e-4f && a <= 1e4f)) ? 1 : 0;
    unsigned long long ball = __ballot(ok);
    isbf = (__popcll(ball) >= 58) ? 1 : 0;
  }

  const int mts[2] = {wave, 7 - wave};   // balanced causal split

  // ---- X fragments (A for V, B for Q^T/K^T) ----
  s8v xf[2][2];
  #pragma unroll
  for (int mi = 0; mi < 2; mi++) {
    const size_t base = (size_t)b * (128 * 64) + (size_t)(mts[mi] * 16 + c16) * 64;
    #pragma unroll
    for (int kt = 0; kt < 2; kt++) {
      const int off = kt * 32 + quad * 8;
      if (isbf) xf[mi][kt] = *(const s8v*)((const unsigned short*)xg + base + off);
      else      xf[mi][kt] = cvt8((const float*)xg + base + off);
    }
  }

  // ---- phase 1: Q^T,K^T (W-major MFMA), V (X-major) ----
  f4 QT[2][4];
  #pragma unroll
  for (int ht = 0; ht < 4; ht++) {
    s8v wqf[2], wkf[2], wvf[2];
    const int woff0 = (ht * 16 + c16) * 64 + quad * 8;
    #pragma unroll
    for (int kt = 0; kt < 2; kt++) {
      const int off = woff0 + kt * 32;
      if (isbf) {
        wqf[kt] = *(const s8v*)((const unsigned short*)wqg + off);
        wkf[kt] = *(const s8v*)((const unsigned short*)wkg + off);
        wvf[kt] = *(const s8v*)((const unsigned short*)wvg + off);
      } else {
        wqf[kt] = cvt8((const float*)wqg + off);
        wkf[kt] = cvt8((const float*)wkg + off);
        wvf[kt] = cvt8((const float*)wvg + off);
      }
    }
    #pragma unroll
    for (int mi = 0; mi < 2; mi++) {
      const int m = mts[mi];
      f4 z = {0.f, 0.f, 0.f, 0.f};
      f4 qt = z, kk = z, vv = z;
      qt = MFMA16(wqf[0], xf[mi][0], qt);  qt = MFMA16(wqf[1], xf[mi][1], qt);
      // swapped operands: lane holds h = ht*16+quad*4+r for s = m*16+c16
      kk = MFMA16(wkf[0], xf[mi][0], kk);  kk = MFMA16(wkf[1], xf[mi][1], kk);
      vv = MFMA16(xf[mi][0], wvf[0], vv);  vv = MFMA16(xf[mi][1], wvf[1], vv);
      QT[mi][ht] = qt;
      {  // K[s][h]: 4 consecutive h -> one 8B swizzled store
        union { unsigned u[2]; s4v v; } pk;
        pk.u[0] = cvtpk(kk[0], kk[1]); pk.u[1] = cvtpk(kk[2], kk[3]);
        *(s4v*)(Ksm + (m * 16 + c16) * 64 + ((ht * 16 + quad * 4) ^ swz)) = pk.v;
      }
      {  // V^T[h][s]: 4 consecutive s -> one 8B swizzled store
        union { unsigned u[2]; s4v v; } pv;
        pv.u[0] = cvtpk(vv[0], vv[1]); pv.u[1] = cvtpk(vv[2], vv[3]);
        *(s4v*)(Vt + (ht * 16 + c16) * 128 + ((m * 16 + quad * 4) ^ swz)) = pv.v;
      }
    }
  }

  // ---- Q B-operand frags, packed lane-local BEFORE the barrier ----
  s8v qb[2][2];
  #pragma unroll
  for (int mi = 0; mi < 2; mi++)
    #pragma unroll
    for (int hp = 0; hp < 2; hp++)
      qb[mi][hp] = mk8(
          cvtpk(QT[mi][2*hp][0]   * 0.125f, QT[mi][2*hp][1]   * 0.125f),
          cvtpk(QT[mi][2*hp][2]   * 0.125f, QT[mi][2*hp][3]   * 0.125f),
          cvtpk(QT[mi][2*hp+1][0] * 0.125f, QT[mi][2*hp+1][1] * 0.125f),
          cvtpk(QT[mi][2*hp+1][2] * 0.125f, QT[mi][2*hp+1][3] * 0.125f));

  __syncthreads();   // only barrier

  // ---- phase 2 per M-tile: S^T -> exp/sum -> O^T = V^T·P^T ----
  #pragma unroll
  for (int mi = 0; mi < 2; mi++) {
    const int m = mts[mi];
    const int q4 = quad * 4;

    f4 S[8];
    #pragma unroll
    for (int nt = 0; nt < 8; nt++) {
      if (nt > m) continue;                 // wave-uniform causal skip
      const short* kr = Ksm + (nt * 16 + c16) * 64;
      f4 s = {0.f, 0.f, 0.f, 0.f};
      s = MFMA16(ld44(kr + ((q4     ) ^ swz), kr + ((q4 + 16) ^ swz)), qb[mi][0], s);
      s = MFMA16(ld44(kr + ((q4 + 32) ^ swz), kr + ((q4 + 48) ^ swz)), qb[mi][1], s);
      S[nt] = s;
    }

    float sum = 0.f;
    #pragma unroll
    for (int nt = 0; nt < 8; nt++) {
      if (nt > m) continue;
      #pragma unroll
      for (int r = 0; r < 4; r++) {
        const bool keep = (nt < m) || (q4 + r <= c16);
        float e = keep ? __expf(S[nt][r]) : 0.0f;
        S[nt][r] = e;
        sum += e;
      }
    }
    sum += __shfl_xor(sum, 16);
    sum += __shfl_xor(sum, 32);
    const float inv = 1.0f / sum;           // normalize in epilogue

    unsigned ppk[8][2];
    #pragma unroll
    for (int nt = 0; nt < 8; nt++) {
      if (nt > m) continue;
      ppk[nt][0] = cvtpk(S[nt][0], S[nt][1]);
      ppk[nt][1] = cvtpk(S[nt][2], S[nt][3]);
    }

    f4 acc[4];
    #pragma unroll
    for (int ht = 0; ht < 4; ht++) { f4 z = {0.f,0.f,0.f,0.f}; acc[ht] = z; }
    const int nchunk = (m >> 1) + 1;
    #pragma unroll
    for (int kt = 0; kt < 4; kt++) {
      if (kt >= nchunk) continue;           // wave-uniform causal K-range
      const bool hb = (2 * kt + 1) <= m;
      const s8v pb = mk8(ppk[2 * kt][0], ppk[2 * kt][1],
                         hb ? ppk[2 * kt + 1][0] : 0u,
                         hb ? ppk[2 * kt + 1][1] : 0u);
      #pragma unroll
      for (int ht = 0; ht < 4; ht++) {
        const short* vr = Vt + (ht * 16 + c16) * 128;
        const s8v va = ld44(vr + ((kt * 32 + q4     ) ^ swz),
                            vr + ((kt * 32 + q4 + 16) ^ swz));
        acc[ht] = MFMA16(va, pb, acc[ht]);
      }
    }

    // epilogue: O^T lane holds 4 consecutive h for query t=c16 -> 8/16B stores
    if (isbf) {
      unsigned short* op = (unsigned short*)outg + (size_t)b * (128 * 64);
      #pragma unroll
      for (int ht = 0; ht < 4; ht++) {
        union { unsigned u[2]; s4v v; } o;
        o.u[0] = cvtpk(acc[ht][0] * inv, acc[ht][1] * inv);
        o.u[1] = cvtpk(acc[ht][2] * inv, acc[ht][3] * inv);
        *(s4v*)(op + (size_t)(m * 16 + c16) * 64 + ht * 16 + q4) = o.v;
      }
    } else {
      float* op = (float*)outg + (size_t)b * (128 * 64);
      #pragma unroll
      for (int ht = 0; ht < 4; ht++) {
        float4 o = {acc[ht][0] * inv, acc[ht][1] * inv,
                    acc[ht][2] * inv, acc[ht][3] * inv};
        *(float4*)(op + (size_t)(m * 16 + c16) * 64 + ht * 16 + q4) = o;
      }
    }
  }
}

extern "C" void kernel_launch(void* const* d_in, const int* in_sizes, int n_in,
                              void* d_out, int out_size, void* d_ws, size_t ws_size,
                              hipStream_t stream) {
  (void)d_ws; (void)ws_size; (void)in_sizes; (void)n_in; (void)out_size;
  attn_head<<<dim3(4096), dim3(256), 0, stream>>>(
      d_in[0], d_in[1], d_in[2], d_in[3], d_out);
}

// Round 17
// 299.833 us; speedup vs baseline: 1.1881x; 1.0357x over previous
//
#include <hip/hip_runtime.h>
#include <hip/hip_bf16.h>

typedef float f4  __attribute__((ext_vector_type(4)));
typedef short s8v __attribute__((ext_vector_type(8)));
typedef short s4v __attribute__((ext_vector_type(4)));

#define MFMA16(a, b, c) __builtin_amdgcn_mfma_f32_16x16x32_bf16((a), (b), (c), 0, 0, 0)

// Packed RNE f32->bf16 pair via compiler intrinsic (emits v_cvt_pk_bf16_f32).
__device__ __forceinline__ unsigned cvtpk(float a, float b) {
  __hip_bfloat162 h2 = __float22bfloat162_rn(make_float2(a, b));
  unsigned u;
  __builtin_memcpy(&u, &h2, 4);
  return u;
}
__device__ __forceinline__ float bf2f(unsigned short s) {
  union { unsigned u; float f; } x; x.u = ((unsigned)s) << 16; return x.f;
}
__device__ __forceinline__ s8v cvt8(const float* p) {
  float4 a = *(const float4*)p;
  float4 b = *(const float4*)(p + 4);
  union { unsigned u[4]; s8v v; } r;
  r.u[0] = cvtpk(a.x, a.y); r.u[1] = cvtpk(a.z, a.w);
  r.u[2] = cvtpk(b.x, b.y); r.u[3] = cvtpk(b.z, b.w);
  return r.v;
}
__device__ __forceinline__ s8v mk8(unsigned a0, unsigned a1, unsigned b0, unsigned b1) {
  union { unsigned u[4]; s8v v; } r;
  r.u[0] = a0; r.u[1] = a1; r.u[2] = b0; r.u[3] = b1;
  return r.v;
}
// Two b64 LDS reads -> one 8-bf16 A-operand (slots j0..3 from p0, j4..7 from p1).
__device__ __forceinline__ s8v ld44(const short* p0, const short* p1) {
  s4v a = *(const s4v*)p0;
  s4v b = *(const s4v*)p1;
  s8v r;
  r[0] = a[0]; r[1] = a[1]; r[2] = a[2]; r[3] = a[3];
  r[4] = b[0]; r[5] = b[1]; r[6] = b[2]; r[7] = b[3];
  return r;
}

// Occupancy steps at VGPR=64 (waves/SIMD halves above 64 — m69). R15: 76 VGPR
// -> 16 waves/CU despite 32KiB LDS (30% occ, 160us). This version cuts live
// state (packed Q^T 16 regs instead of f4 32; fused S->exp->PV per kt-chunk,
// no S[8]/ppk[8] arrays) so natural pressure ~55-60, then caps at 64 via
// (256,4) -> 8 waves/SIMD VGPR-wise, 5 blocks/CU LDS-wise (20 waves, 62.5%).
__global__ __launch_bounds__(256, 4)
void attn_head(const void* __restrict__ xg, const void* __restrict__ wqg,
               const void* __restrict__ wkg, const void* __restrict__ wvg,
               void* __restrict__ outg) {
  // LDS exactly 32768 B -> 5 blocks/CU.
  // Ks: K[s][h] at s*64 + (h ^ ((s&15)<<2))   (XOR swizzle, 8B granules)
  // Vt: V^T[h][s] at h*128 + (s ^ ((h&15)<<2))
  // All 8B accesses conflict-free (R5/R6/R15 measured SQ_LDS_BANK_CONFLICT=0).
  __shared__ __align__(16) short smem[16384];
  short* Ksm = smem;           // 128*64 shorts
  short* Vt  = smem + 8192;    // 64*128 shorts

  const int tid  = threadIdx.x;
  const int wave = tid >> 6;
  const int lane = tid & 63;
  const int c16  = lane & 15;
  const int quad = lane >> 4;
  const int b    = blockIdx.x;
  const int swz  = c16 << 2;

  // ---- barrier-free dtype detect: every wave samples the SAME 64 shorts ----
  int isbf;
  {
    const unsigned short* w = (const unsigned short*)wqg;
    float f = bf2f(w[lane]);
    float a = fabsf(f);
    int ok = (f == 0.0f || (a >= 1e-4f && a <= 1e4f)) ? 1 : 0;
    unsigned long long ball = __ballot(ok);
    isbf = (__popcll(ball) >= 58) ? 1 : 0;
  }

  const int mts[2] = {wave, 7 - wave};   // balanced causal split

  // ---- X fragments (A for V, B for Q^T/K^T) ----
  s8v xf[2][2];
  #pragma unroll
  for (int mi = 0; mi < 2; mi++) {
    const size_t base = (size_t)b * (128 * 64) + (size_t)(mts[mi] * 16 + c16) * 64;
    #pragma unroll
    for (int kt = 0; kt < 2; kt++) {
      const int off = kt * 32 + quad * 8;
      if (isbf) xf[mi][kt] = *(const s8v*)((const unsigned short*)xg + base + off);
      else      xf[mi][kt] = cvt8((const float*)xg + base + off);
    }
  }

  // ---- phase 1: Q^T (packed to bf16 immediately, 16 regs), K,V -> LDS ----
  unsigned qpk[2][4][2];   // [mi][ht][pair]: scaled Q^T, slot-layout packed
  #pragma unroll
  for (int ht = 0; ht < 4; ht++) {
    s8v wqf[2], wkf[2], wvf[2];
    const int woff0 = (ht * 16 + c16) * 64 + quad * 8;
    #pragma unroll
    for (int kt = 0; kt < 2; kt++) {
      const int off = woff0 + kt * 32;
      if (isbf) {
        wqf[kt] = *(const s8v*)((const unsigned short*)wqg + off);
        wkf[kt] = *(const s8v*)((const unsigned short*)wkg + off);
        wvf[kt] = *(const s8v*)((const unsigned short*)wvg + off);
      } else {
        wqf[kt] = cvt8((const float*)wqg + off);
        wkf[kt] = cvt8((const float*)wkg + off);
        wvf[kt] = cvt8((const float*)wvg + off);
      }
    }
    #pragma unroll
    for (int mi = 0; mi < 2; mi++) {
      const int m = mts[mi];
      f4 z = {0.f, 0.f, 0.f, 0.f};
      f4 qt = z, kk = z, vv = z;
      qt = MFMA16(wqf[0], xf[mi][0], qt);  qt = MFMA16(wqf[1], xf[mi][1], qt);
      // swapped operands: lane holds h = ht*16+quad*4+r for s = m*16+c16
      kk = MFMA16(wkf[0], xf[mi][0], kk);  kk = MFMA16(wkf[1], xf[mi][1], kk);
      vv = MFMA16(xf[mi][0], wvf[0], vv);  vv = MFMA16(xf[mi][1], wvf[1], vv);
      qpk[mi][ht][0] = cvtpk(qt[0] * 0.125f, qt[1] * 0.125f);
      qpk[mi][ht][1] = cvtpk(qt[2] * 0.125f, qt[3] * 0.125f);
      {  // K[s][h]: 4 consecutive h -> one 8B swizzled store
        union { unsigned u[2]; s4v v; } pk;
        pk.u[0] = cvtpk(kk[0], kk[1]); pk.u[1] = cvtpk(kk[2], kk[3]);
        *(s4v*)(Ksm + (m * 16 + c16) * 64 + ((ht * 16 + quad * 4) ^ swz)) = pk.v;
      }
      {  // V^T[h][s]: 4 consecutive s -> one 8B swizzled store
        union { unsigned u[2]; s4v v; } pv;
        pv.u[0] = cvtpk(vv[0], vv[1]); pv.u[1] = cvtpk(vv[2], vv[3]);
        *(s4v*)(Vt + (ht * 16 + c16) * 128 + ((m * 16 + quad * 4) ^ swz)) = pv.v;
      }
    }
  }

  __syncthreads();   // only barrier

  // ---- phase 2 per M-tile: fused per-kt S^T -> exp -> P^T -> PV ----
  // No S[8]/ppk[8] arrays: one kt-chunk (2 key-tiles) lives at a time.
  // Normalization deferred to epilogue, so P enters PV unnormalized and
  // the row-sum accumulates alongside.
  #pragma unroll
  for (int mi = 0; mi < 2; mi++) {
    const int m = mts[mi];
    const int q4 = quad * 4;
    const s8v qb0 = mk8(qpk[mi][0][0], qpk[mi][0][1], qpk[mi][1][0], qpk[mi][1][1]);
    const s8v qb1 = mk8(qpk[mi][2][0], qpk[mi][2][1], qpk[mi][3][0], qpk[mi][3][1]);

    f4 acc[4];
    #pragma unroll
    for (int ht = 0; ht < 4; ht++) { f4 z = {0.f,0.f,0.f,0.f}; acc[ht] = z; }
    float sum = 0.f;
    const int nchunk = (m >> 1) + 1;

    #pragma unroll
    for (int kt = 0; kt < 4; kt++) {
      if (kt >= nchunk) continue;           // wave-uniform causal K-range
      const int nt0 = 2 * kt, nt1 = 2 * kt + 1;
      const bool hb = nt1 <= m;             // wave-uniform

      f4 z = {0.f, 0.f, 0.f, 0.f};
      f4 s0 = z, s1 = z;
      {
        const short* kr = Ksm + (nt0 * 16 + c16) * 64;
        s0 = MFMA16(ld44(kr + ((q4     ) ^ swz), kr + ((q4 + 16) ^ swz)), qb0, s0);
        s0 = MFMA16(ld44(kr + ((q4 + 32) ^ swz), kr + ((q4 + 48) ^ swz)), qb1, s0);
      }
      if (hb) {
        const short* kr = Ksm + (nt1 * 16 + c16) * 64;
        s1 = MFMA16(ld44(kr + ((q4     ) ^ swz), kr + ((q4 + 16) ^ swz)), qb0, s1);
        s1 = MFMA16(ld44(kr + ((q4 + 32) ^ swz), kr + ((q4 + 48) ^ swz)), qb1, s1);
      }
      #pragma unroll
      for (int r = 0; r < 4; r++) {
        const bool k0 = (nt0 < m) || (q4 + r <= c16);
        float e0 = k0 ? __expf(s0[r]) : 0.0f;
        s0[r] = e0; sum += e0;
      }
      if (hb) {
        #pragma unroll
        for (int r = 0; r < 4; r++) {
          const bool k1 = (nt1 < m) || (q4 + r <= c16);
          float e1 = k1 ? __expf(s1[r]) : 0.0f;
          s1[r] = e1; sum += e1;
        }
      }
      // s1 stays all-zero when !hb -> upper half of pb packs to 0 (correct).
      const s8v pb = mk8(cvtpk(s0[0], s0[1]), cvtpk(s0[2], s0[3]),
                         cvtpk(s1[0], s1[1]), cvtpk(s1[2], s1[3]));
      #pragma unroll
      for (int ht = 0; ht < 4; ht++) {
        const short* vr = Vt + (ht * 16 + c16) * 128;
        const s8v va = ld44(vr + ((kt * 32 + q4     ) ^ swz),
                            vr + ((kt * 32 + q4 + 16) ^ swz));
        acc[ht] = MFMA16(va, pb, acc[ht]);
      }
    }

    sum += __shfl_xor(sum, 16);
    sum += __shfl_xor(sum, 32);
    const float inv = 1.0f / sum;           // normalize in epilogue

    // epilogue: O^T lane holds 4 consecutive h for query t=c16 -> 8/16B stores
    if (isbf) {
      unsigned short* op = (unsigned short*)outg + (size_t)b * (128 * 64);
      #pragma unroll
      for (int ht = 0; ht < 4; ht++) {
        union { unsigned u[2]; s4v v; } o;
        o.u[0] = cvtpk(acc[ht][0] * inv, acc[ht][1] * inv);
        o.u[1] = cvtpk(acc[ht][2] * inv, acc[ht][3] * inv);
        *(s4v*)(op + (size_t)(m * 16 + c16) * 64 + ht * 16 + q4) = o.v;
      }
    } else {
      float* op = (float*)outg + (size_t)b * (128 * 64);
      #pragma unroll
      for (int ht = 0; ht < 4; ht++) {
        float4 o = {acc[ht][0] * inv, acc[ht][1] * inv,
                    acc[ht][2] * inv, acc[ht][3] * inv};
        *(float4*)(op + (size_t)(m * 16 + c16) * 64 + ht * 16 + q4) = o;
      }
    }
  }
}

extern "C" void kernel_launch(void* const* d_in, const int* in_sizes, int n_in,
                              void* d_out, int out_size, void* d_ws, size_t ws_size,
                              hipStream_t stream) {
  (void)d_ws; (void)ws_size; (void)in_sizes; (void)n_in; (void)out_size;
  attn_head<<<dim3(4096), dim3(256), 0, stream>>>(
      d_in[0], d_in[1], d_in[2], d_in[3], d_out);
}